// Round 2
// baseline (347.039 us; speedup 1.0000x reference)
//
#include <hip/hip_runtime.h>
#include <cstdint>

typedef __attribute__((ext_vector_type(8))) short bf16x8;
typedef __attribute__((ext_vector_type(4))) float f32x4;
typedef unsigned short u16;
typedef uint32_t u32;

#define HW56 56
#define HWSQ 3136       // 56*56
#define MTOT 200704     // 64*3136
#define CCH 128
#define BM 128
#define NSTEP 18        // 9 taps * 2 K-halves (BK=64)

__device__ __forceinline__ u16 f2bf(float f) {
  u32 u = __builtin_bit_cast(u32, f);
  u = (u + 0x7fffu + ((u >> 16) & 1u)) >> 16;   // RNE
  return (u16)u;
}
__device__ __forceinline__ float bf2f(u16 h) {
  return __builtin_bit_cast(float, (u32)h << 16);
}
__device__ __forceinline__ void gload16(const void* g, void* l) {
  __builtin_amdgcn_global_load_lds((const __attribute__((address_space(1))) void*)g,
                                   (__attribute__((address_space(3))) void*)l, 16, 0, 0);
}

// ---------- pack x: NCHW f32 -> NHWC bf16 ----------
__global__ __launch_bounds__(256) void pack_x_kernel(const float* __restrict__ x,
                                                     u16* __restrict__ xb) {
  const int lane = threadIdx.x & 63;
  const int wv = threadIdx.x >> 6;            // wave 0..3 -> channel quarter
  const int pos = blockIdx.x * 64 + lane;     // grid = MTOT/64
  const int n = pos / HWSQ, hw = pos % HWSQ;
  const float* src = x + (size_t)n * (CCH * HWSQ) + hw;   // reads coalesced over hw
  u16* dst = xb + (size_t)pos * CCH + wv * 32;
#pragma unroll
  for (int k = 0; k < 4; ++k) {
    u32 vv[4];
#pragma unroll
    for (int q = 0; q < 4; ++q) {
      const int c0 = wv * 32 + k * 8 + q * 2;
      u16 b0 = f2bf(src[(size_t)c0 * HWSQ]);
      u16 b1 = f2bf(src[(size_t)(c0 + 1) * HWSQ]);
      vv[q] = (u32)b0 | ((u32)b1 << 16);
    }
    uint4 v; v.x = vv[0]; v.y = vv[1]; v.z = vv[2]; v.w = vv[3];
    *(uint4*)(dst + k * 8) = v;               // 16B per lane
  }
}

// ---------- pack weights: fold BN scale, [O][I][3][3] f32 -> [tap][oc][ic] bf16 ----------
__global__ __launch_bounds__(256) void pack_w_kernel(
    const float* __restrict__ w1, const float* __restrict__ w2,
    const float* __restrict__ g1, const float* __restrict__ be1,
    const float* __restrict__ mu1, const float* __restrict__ va1,
    const float* __restrict__ g2, const float* __restrict__ be2,
    const float* __restrict__ mu2, const float* __restrict__ va2,
    u16* __restrict__ w1p, u16* __restrict__ w2p,
    float* __restrict__ b1, float* __restrict__ b2, float* __restrict__ zp) {
  const int idx = blockIdx.x * 256 + threadIdx.x;   // grid = 294912/256
  if (idx < 2 * 147456) {
    const int which = idx >= 147456;
    const int j = which ? idx - 147456 : idx;
    const int t = j >> 14;            // tap 0..8
    const int oc = (j >> 7) & 127;
    const int ic = j & 127;
    const float* w = which ? w2 : w1;
    const float* gg = which ? g2 : g1;
    const float* va = which ? va2 : va1;
    const float s = gg[oc] * rsqrtf(va[oc] + 1e-5f);
    const float val = w[(size_t)(oc * 128 + ic) * 9 + t] * s;
    (which ? w2p : w1p)[j] = f2bf(val);
  }
  if (blockIdx.x == 0) {
    const int t = threadIdx.x;
    if (t < 128) {
      const float s1 = g1[t] * rsqrtf(va1[t] + 1e-5f);
      b1[t] = be1[t] - mu1[t] * s1;
      const float s2 = g2[t] * rsqrtf(va2[t] + 1e-5f);
      b2[t] = be2[t] - mu2[t] * s2;
    }
    if (t < 64) zp[t] = 0.f;          // 256B zero page (ws is re-poisoned each launch)
  }
}

// ---------- implicit-GEMM conv 3x3 (pad=1) with fused BN(+ReLU)(+residual) ----------
// src: NHWC bf16 activations; wp: [tap][oc][ic] bf16 (BN scale folded)
// PASS 1: out = relu(acc + b) -> bf16 NHWC (outb)
// PASS 2: out = relu(acc + b + residual) -> f32 NCHW (outf), via LDS transpose
template <int PASS>
__global__ __launch_bounds__(256, 2) void conv_mfma(
    const u16* __restrict__ src, const u16* __restrict__ wp,
    const float* __restrict__ bias, const u16* __restrict__ resid,
    u16* __restrict__ outb, float* __restrict__ outf,
    const char* __restrict__ zp) {
  // LDS: A0 | A1 | B0 | B1 (16KB each). Rows of 128B (64 ic bf16), XOR-swizzled
  // content: slot s of row r holds source 16B-group s^(r&7).
  __shared__ __align__(1024) char lds[65536];
  const int tid = threadIdx.x;
  const int wave = tid >> 6, lane = tid & 63;
  const int m0 = blockIdx.x * BM;             // grid = MTOT/BM
  const int wm = wave >> 1, wn = wave & 1;    // 2x2 wave grid, 64x64 tile each

  // Per-thread staging state: 4 rows (8-row groups), one 16B group each.
  const int g = lane & 7;
  int ah[4], aw[4];
  long long aoff[4], boff[4];
#pragma unroll
  for (int i = 0; i < 4; ++i) {
    const int r = wave * 32 + i * 8 + (lane >> 3);  // row 0..127
    const int pos = m0 + r;
    const int hw = pos % HWSQ;
    ah[i] = hw / HW56;
    aw[i] = hw % HW56;
    const int gsw = g ^ (r & 7);                    // pre-swizzled source group
    aoff[i] = (long long)pos * 256 + gsw * 16;      // NHWC row = 256B
    boff[i] = (long long)r * 256 + gsw * 16;        // w row (oc) = 256B
  }
  const char* srcb = (const char*)src;
  const char* wpb = (const char*)wp;

  auto stage = [&](int buf, int s) {
    const int t = s >> 1, kh = s & 1;
    const int dyo = t / 3 - 1, dxo = t % 3 - 1;
    const long long adelta = (long long)(dyo * HW56 + dxo) * 256 + kh * 128;
    const long long bdelta = (long long)t * 32768 + kh * 128;
    char* ldsA = lds + buf * 16384;
    char* ldsB = lds + 32768 + buf * 16384;
#pragma unroll
    for (int i = 0; i < 4; ++i) {
      const int hh = ah[i] + dyo, ww = aw[i] + dxo;
      const bool valid = ((unsigned)hh < 56u) & ((unsigned)ww < 56u);
      const char* ap = valid ? (srcb + aoff[i] + adelta) : zp;  // zero-pad via zero page
      gload16(ap, ldsA + (wave * 32 + i * 8) * 128);            // LDS dest wave-uniform
      gload16(wpb + boff[i] + bdelta, ldsB + (wave * 32 + i * 8) * 128);
    }
  };

  f32x4 acc[4][4];
#pragma unroll
  for (int m = 0; m < 4; ++m)
#pragma unroll
    for (int n = 0; n < 4; ++n) {
      f32x4 z = {0.f, 0.f, 0.f, 0.f};
      acc[m][n] = z;
    }

  auto compute = [&](int buf) {
    const char* ldsA = lds + buf * 16384;
    const char* ldsB = lds + 32768 + buf * 16384;
    bf16x8 a[4][2], b[4][2];
#pragma unroll
    for (int m = 0; m < 4; ++m) {
      const int row = wm * 64 + m * 16 + (lane & 15);
      const char* rp = ldsA + row * 128;
      const int sw = row & 7;
#pragma unroll
      for (int ks = 0; ks < 2; ++ks) {
        const int gg = ks * 4 + (lane >> 4);                  // k-group: ks*32 + (lane>>4)*8
        a[m][ks] = *(const bf16x8*)(rp + ((gg ^ sw) << 4));   // swizzled ds_read_b128
      }
    }
#pragma unroll
    for (int n = 0; n < 4; ++n) {
      const int row = wn * 64 + n * 16 + (lane & 15);
      const char* rp = ldsB + row * 128;
      const int sw = row & 7;
#pragma unroll
      for (int ks = 0; ks < 2; ++ks) {
        const int gg = ks * 4 + (lane >> 4);
        b[n][ks] = *(const bf16x8*)(rp + ((gg ^ sw) << 4));
      }
    }
#pragma unroll
    for (int ks = 0; ks < 2; ++ks)
#pragma unroll
      for (int m = 0; m < 4; ++m)
#pragma unroll
        for (int n = 0; n < 4; ++n)
          acc[m][n] = __builtin_amdgcn_mfma_f32_16x16x32_bf16(a[m][ks], b[n][ks],
                                                              acc[m][n], 0, 0, 0);
  };

  stage(0, 0);
  __syncthreads();
#pragma unroll
  for (int s = 0; s < NSTEP; ++s) {
    const int cur = s & 1;
    if (s + 1 < NSTEP) stage(cur ^ 1, s + 1);   // prefetch next tile into other buffer
    compute(cur);
    __syncthreads();                             // drains vmcnt+lgkmcnt (m97 structure)
  }

  if (PASS == 1) {
#pragma unroll
    for (int nf = 0; nf < 4; ++nf) {
      const int oc = wn * 64 + nf * 16 + (lane & 15);
      const float bb = bias[oc];
#pragma unroll
      for (int m = 0; m < 4; ++m) {
        const int pbase = m0 + wm * 64 + m * 16 + (lane >> 4) * 4;
#pragma unroll
        for (int r = 0; r < 4; ++r) {
          float v = acc[m][nf][r] + bb;
          v = fmaxf(v, 0.f);
          outb[(size_t)(pbase + r) * CCH + oc] = f2bf(v);
        }
      }
    }
  } else {
    // epilogue: bias + residual + relu, then per-wave LDS transpose -> coalesced NCHW f32
    float* tl = (float*)(lds + wave * 4352);     // [64][17] f32, wave-private
    const int posr = m0 + wm * 64 + lane;
    const int nimg = posr / HWSQ, hwr = posr % HWSQ;
#pragma unroll
    for (int nf = 0; nf < 4; ++nf) {
      const int oc = wn * 64 + nf * 16 + (lane & 15);
      const float bb = bias[oc];
#pragma unroll
      for (int m = 0; m < 4; ++m) {
#pragma unroll
        for (int r = 0; r < 4; ++r) {
          const int row = m * 16 + (lane >> 4) * 4 + r;
          const int pos = m0 + wm * 64 + row;
          const float rv = bf2f(resid[(size_t)pos * CCH + oc]);
          float v = acc[m][nf][r] + bb + rv;
          tl[row * 17 + (lane & 15)] = fmaxf(v, 0.f);
        }
      }
      // compiler inserts lgkmcnt waits for the within-wave LDS RAW/WAR here
#pragma unroll
      for (int oci = 0; oci < 16; ++oci) {
        const float v = tl[lane * 17 + oci];
        const int oc2 = wn * 64 + nf * 16 + oci;
        outf[(size_t)(nimg * CCH + oc2) * HWSQ + hwr] = v;   // 64 consecutive hw per store
      }
    }
  }
}

extern "C" void kernel_launch(void* const* d_in, const int* in_sizes, int n_in,
                              void* d_out, int out_size, void* d_ws, size_t ws_size,
                              hipStream_t stream) {
  const float* x = (const float*)d_in[0];
  const float* w1 = (const float*)d_in[1];
  const float* w2 = (const float*)d_in[2];
  const float* g1 = (const float*)d_in[3];
  const float* be1 = (const float*)d_in[4];
  const float* mu1 = (const float*)d_in[5];
  const float* va1 = (const float*)d_in[6];
  const float* g2 = (const float*)d_in[7];
  const float* be2 = (const float*)d_in[8];
  const float* mu2 = (const float*)d_in[9];
  const float* va2 = (const float*)d_in[10];

  char* ws = (char*)d_ws;
  u16* xb  = (u16*)(ws + 0);                    // 200704*128*2 = 51,380,224 B
  u16* o1b = (u16*)(ws + 51380224);             // 51,380,224 B
  u16* w1p = (u16*)(ws + 102760448);            // 294,912 B
  u16* w2p = (u16*)(ws + 103055360);            // 294,912 B
  float* b1 = (float*)(ws + 103350272);         // 512 B
  float* b2 = (float*)(ws + 103350784);         // 512 B
  float* zp = (float*)(ws + 103351296);         // 256 B zero page

  pack_x_kernel<<<MTOT / 64, 256, 0, stream>>>(x, xb);
  pack_w_kernel<<<1152, 256, 0, stream>>>(w1, w2, g1, be1, mu1, va1,
                                          g2, be2, mu2, va2, w1p, w2p, b1, b2, zp);
  conv_mfma<1><<<MTOT / BM, 256, 0, stream>>>(xb, w1p, b1, nullptr, o1b, nullptr,
                                              (const char*)zp);
  conv_mfma<2><<<MTOT / BM, 256, 0, stream>>>(o1b, w2p, b2, xb, nullptr, (float*)d_out,
                                              (const char*)zp);
}

// Round 3
// 335.927 us; speedup vs baseline: 1.0331x; 1.0331x over previous
//
#include <hip/hip_runtime.h>
#include <cstdint>

typedef __attribute__((ext_vector_type(8))) short bf16x8;
typedef __attribute__((ext_vector_type(4))) float f32x4;
typedef unsigned short u16;
typedef uint32_t u32;

#define HW56 56
#define HWSQ 3136       // 56*56
#define MTOT 200704     // 64*3136
#define CCH 128
#define BM 128
#define NSTEP 18        // 9 taps * 2 K-halves (BK=64)
#define NBLK (MTOT / BM)        // 1568 = 8 * 196
#define NB_PER_XCD (NBLK / 8)   // 196

__device__ __forceinline__ u16 f2bf(float f) {
  u32 u = __builtin_bit_cast(u32, f);
  u = (u + 0x7fffu + ((u >> 16) & 1u)) >> 16;   // RNE
  return (u16)u;
}
__device__ __forceinline__ float bf2f(u16 h) {
  return __builtin_bit_cast(float, (u32)h << 16);
}
__device__ __forceinline__ void gload16(const void* g, void* l) {
  __builtin_amdgcn_global_load_lds((const __attribute__((address_space(1))) void*)g,
                                   (__attribute__((address_space(3))) void*)l, 16, 0, 0);
}

// ---------- pack x: NCHW f32 -> NHWC bf16, LDS-transposed so BOTH sides coalesce ----
__global__ __launch_bounds__(256) void pack_x_kernel(const float* __restrict__ x,
                                                     u16* __restrict__ xb) {
  __shared__ u16 t[128 * 65];                 // [c][pos], stride 65 (bank-friendly)
  const int tid = threadIdx.x;
  const int lane = tid & 63, wv = tid >> 6;
  const int p0 = blockIdx.x * 64;             // 64 pos, one image (3136 % 64 == 0)
  const int n = p0 / HWSQ, hw0 = p0 % HWSQ;
  const float* src = x + (size_t)(n * CCH) * HWSQ + hw0;
#pragma unroll
  for (int k = 0; k < 32; ++k) {              // coalesced 256B reads per instr
    const int c = wv * 32 + k;
    t[c * 65 + lane] = f2bf(src[(size_t)c * HWSQ + lane]);
  }
  __syncthreads();
  u16* dst = xb + (size_t)p0 * CCH;
#pragma unroll
  for (int it = 0; it < 4; ++it) {            // coalesced 1KB writes per wave-instr
    const int u = it * 256 + tid;
    const int pos = u >> 4, ch0 = (u & 15) * 8;
    u32 vv[4];
#pragma unroll
    for (int q = 0; q < 4; ++q) {
      const u16 a = t[(ch0 + 2 * q) * 65 + pos];
      const u16 b = t[(ch0 + 2 * q + 1) * 65 + pos];
      vv[q] = (u32)a | ((u32)b << 16);
    }
    uint4 v; v.x = vv[0]; v.y = vv[1]; v.z = vv[2]; v.w = vv[3];
    *(uint4*)(dst + (size_t)pos * CCH + ch0) = v;
  }
}

// ---------- pack weights: fold BN scale, [O][I][3][3] f32 -> [tap][oc][ic] bf16 ----------
__global__ __launch_bounds__(256) void pack_w_kernel(
    const float* __restrict__ w1, const float* __restrict__ w2,
    const float* __restrict__ g1, const float* __restrict__ be1,
    const float* __restrict__ mu1, const float* __restrict__ va1,
    const float* __restrict__ g2, const float* __restrict__ be2,
    const float* __restrict__ mu2, const float* __restrict__ va2,
    u16* __restrict__ w1p, u16* __restrict__ w2p,
    float* __restrict__ b1, float* __restrict__ b2, float* __restrict__ zp) {
  const int idx = blockIdx.x * 256 + threadIdx.x;   // grid = 294912/256
  if (idx < 2 * 147456) {
    const int which = idx >= 147456;
    const int j = which ? idx - 147456 : idx;
    const int t = j >> 14;            // tap 0..8
    const int oc = (j >> 7) & 127;
    const int ic = j & 127;
    const float* w = which ? w2 : w1;
    const float* gg = which ? g2 : g1;
    const float* va = which ? va2 : va1;
    const float s = gg[oc] * rsqrtf(va[oc] + 1e-5f);
    const float val = w[(size_t)(oc * 128 + ic) * 9 + t] * s;
    (which ? w2p : w1p)[j] = f2bf(val);
  }
  if (blockIdx.x == 0) {
    const int t = threadIdx.x;
    if (t < 128) {
      const float s1 = g1[t] * rsqrtf(va1[t] + 1e-5f);
      b1[t] = be1[t] - mu1[t] * s1;
      const float s2 = g2[t] * rsqrtf(va2[t] + 1e-5f);
      b2[t] = be2[t] - mu2[t] * s2;
    }
    if (t < 64) zp[t] = 0.f;          // 256B zero page (ws is re-poisoned each launch)
  }
}

// ---------- implicit-GEMM conv 3x3 (pad=1) with fused BN(+ReLU)(+residual) ----------
// src: NHWC bf16 activations; wp: [tap][oc][ic] bf16 (BN scale folded)
// PASS 1: out = relu(acc + b) -> bf16 NHWC (outb)
// PASS 2: out = relu(acc + b + residual) -> f32 NCHW (outf), via LDS transpose
template <int PASS>
__global__ __launch_bounds__(256, 2) void conv_mfma(
    const u16* __restrict__ src, const u16* __restrict__ wp,
    const float* __restrict__ bias, const u16* __restrict__ resid,
    u16* __restrict__ outb, float* __restrict__ outf,
    const char* __restrict__ zp) {
  // LDS: A0 | A1 | B0 | B1 (16KB each). Rows of 128B (64 ic bf16), XOR-swizzled
  // content: slot s of row r holds source 16B-group s^(r&7).
  __shared__ __align__(1024) char lds[65536];
  const int tid = threadIdx.x;
  const int wave = tid >> 6, lane = tid & 63;
  // T1: XCD-chunked bijective swizzle (1568 % 8 == 0) — neighbor tiles share
  // 3x3 halos + weights -> keep them on one XCD's L2.
  const int bid = blockIdx.x;
  const int swz = (bid & 7) * NB_PER_XCD + (bid >> 3);
  const int m0 = swz * BM;
  const int wm = wave >> 1, wn = wave & 1;    // 2x2 wave grid, 64x64 tile each

  // Per-thread staging state: 4 rows (8-row groups), one 16B group each.
  const int g = lane & 7;
  int ah[4], aw[4];
  long long aoff[4], boff[4];
#pragma unroll
  for (int i = 0; i < 4; ++i) {
    const int r = wave * 32 + i * 8 + (lane >> 3);  // row 0..127
    const int pos = m0 + r;
    const int hw = pos % HWSQ;
    ah[i] = hw / HW56;
    aw[i] = hw % HW56;
    const int gsw = g ^ (r & 7);                    // pre-swizzled source group
    aoff[i] = (long long)pos * 256 + gsw * 16;      // NHWC row = 256B
    boff[i] = (long long)r * 256 + gsw * 16;        // w row (oc) = 256B
  }
  const char* srcb = (const char*)src;
  const char* wpb = (const char*)wp;

  auto stage = [&](int buf, int s) {
    const int t = s >> 1, kh = s & 1;
    const int dyo = t / 3 - 1, dxo = t % 3 - 1;
    const long long adelta = (long long)(dyo * HW56 + dxo) * 256 + kh * 128;
    const long long bdelta = (long long)t * 32768 + kh * 128;
    char* ldsA = lds + buf * 16384;
    char* ldsB = lds + 32768 + buf * 16384;
#pragma unroll
    for (int i = 0; i < 4; ++i) {
      const int hh = ah[i] + dyo, ww = aw[i] + dxo;
      const bool valid = ((unsigned)hh < 56u) & ((unsigned)ww < 56u);
      const char* ap = valid ? (srcb + aoff[i] + adelta) : zp;  // zero-pad via zero page
      gload16(ap, ldsA + (wave * 32 + i * 8) * 128);            // LDS dest wave-uniform
      gload16(wpb + boff[i] + bdelta, ldsB + (wave * 32 + i * 8) * 128);
    }
  };

  f32x4 acc[4][4];
#pragma unroll
  for (int m = 0; m < 4; ++m)
#pragma unroll
    for (int n = 0; n < 4; ++n) {
      f32x4 z = {0.f, 0.f, 0.f, 0.f};
      acc[m][n] = z;
    }

  auto compute = [&](int buf) {
    const char* ldsA = lds + buf * 16384;
    const char* ldsB = lds + 32768 + buf * 16384;
    bf16x8 a[4][2], b[4][2];
#pragma unroll
    for (int m = 0; m < 4; ++m) {
      const int row = wm * 64 + m * 16 + (lane & 15);
      const char* rp = ldsA + row * 128;
      const int sw = row & 7;
#pragma unroll
      for (int ks = 0; ks < 2; ++ks) {
        const int gg = ks * 4 + (lane >> 4);                  // k-group: ks*32 + (lane>>4)*8
        a[m][ks] = *(const bf16x8*)(rp + ((gg ^ sw) << 4));   // swizzled ds_read_b128
      }
    }
#pragma unroll
    for (int n = 0; n < 4; ++n) {
      const int row = wn * 64 + n * 16 + (lane & 15);
      const char* rp = ldsB + row * 128;
      const int sw = row & 7;
#pragma unroll
      for (int ks = 0; ks < 2; ++ks) {
        const int gg = ks * 4 + (lane >> 4);
        b[n][ks] = *(const bf16x8*)(rp + ((gg ^ sw) << 4));
      }
    }
#pragma unroll
    for (int ks = 0; ks < 2; ++ks)
#pragma unroll
      for (int m = 0; m < 4; ++m)
#pragma unroll
        for (int n = 0; n < 4; ++n)
          acc[m][n] = __builtin_amdgcn_mfma_f32_16x16x32_bf16(a[m][ks], b[n][ks],
                                                              acc[m][n], 0, 0, 0);
  };

  stage(0, 0);
  __syncthreads();
#pragma unroll
  for (int s = 0; s < NSTEP; ++s) {
    const int cur = s & 1;
    if (s + 1 < NSTEP) stage(cur ^ 1, s + 1);   // prefetch next tile into other buffer
    compute(cur);
    __syncthreads();                             // drains vmcnt+lgkmcnt (m97 structure)
  }

  if (PASS == 1) {
#pragma unroll
    for (int nf = 0; nf < 4; ++nf) {
      const int oc = wn * 64 + nf * 16 + (lane & 15);
      const float bb = bias[oc];
#pragma unroll
      for (int m = 0; m < 4; ++m) {
        const int pbase = m0 + wm * 64 + m * 16 + (lane >> 4) * 4;
#pragma unroll
        for (int r = 0; r < 4; ++r) {
          float v = acc[m][nf][r] + bb;
          v = fmaxf(v, 0.f);
          outb[(size_t)(pbase + r) * CCH + oc] = f2bf(v);
        }
      }
    }
  } else {
    // epilogue: bias + residual + relu, then per-wave LDS transpose -> coalesced NCHW f32
    float* tl = (float*)(lds + wave * 4352);     // [64][17] f32, wave-private
    const int posr = m0 + wm * 64 + lane;
    const int nimg = posr / HWSQ, hwr = posr % HWSQ;
#pragma unroll
    for (int nf = 0; nf < 4; ++nf) {
      const int oc = wn * 64 + nf * 16 + (lane & 15);
      const float bb = bias[oc];
#pragma unroll
      for (int m = 0; m < 4; ++m) {
#pragma unroll
        for (int r = 0; r < 4; ++r) {
          const int row = m * 16 + (lane >> 4) * 4 + r;
          const int pos = m0 + wm * 64 + row;
          const float rv = bf2f(resid[(size_t)pos * CCH + oc]);
          float v = acc[m][nf][r] + bb + rv;
          tl[row * 17 + (lane & 15)] = fmaxf(v, 0.f);
        }
      }
      // compiler inserts lgkmcnt waits for the within-wave LDS RAW/WAR here
#pragma unroll
      for (int oci = 0; oci < 16; ++oci) {
        const float v = tl[lane * 17 + oci];
        const int oc2 = wn * 64 + nf * 16 + oci;
        outf[(size_t)(nimg * CCH + oc2) * HWSQ + hwr] = v;   // 64 consecutive hw per store
      }
    }
  }
}

extern "C" void kernel_launch(void* const* d_in, const int* in_sizes, int n_in,
                              void* d_out, int out_size, void* d_ws, size_t ws_size,
                              hipStream_t stream) {
  const float* x = (const float*)d_in[0];
  const float* w1 = (const float*)d_in[1];
  const float* w2 = (const float*)d_in[2];
  const float* g1 = (const float*)d_in[3];
  const float* be1 = (const float*)d_in[4];
  const float* mu1 = (const float*)d_in[5];
  const float* va1 = (const float*)d_in[6];
  const float* g2 = (const float*)d_in[7];
  const float* be2 = (const float*)d_in[8];
  const float* mu2 = (const float*)d_in[9];
  const float* va2 = (const float*)d_in[10];

  char* ws = (char*)d_ws;
  u16* xb  = (u16*)(ws + 0);                    // 200704*128*2 = 51,380,224 B
  u16* o1b = (u16*)(ws + 51380224);             // 51,380,224 B
  u16* w1p = (u16*)(ws + 102760448);            // 294,912 B
  u16* w2p = (u16*)(ws + 103055360);            // 294,912 B
  float* b1 = (float*)(ws + 103350272);         // 512 B
  float* b2 = (float*)(ws + 103350784);         // 512 B
  float* zp = (float*)(ws + 103351296);         // 256 B zero page

  pack_x_kernel<<<MTOT / 64, 256, 0, stream>>>(x, xb);
  pack_w_kernel<<<1152, 256, 0, stream>>>(w1, w2, g1, be1, mu1, va1,
                                          g2, be2, mu2, va2, w1p, w2p, b1, b2, zp);
  conv_mfma<1><<<NBLK, 256, 0, stream>>>(xb, w1p, b1, nullptr, o1b, nullptr,
                                         (const char*)zp);
  conv_mfma<2><<<NBLK, 256, 0, stream>>>(o1b, w2p, b2, xb, nullptr, (float*)d_out,
                                         (const char*)zp);
}

// Round 4
// 322.692 us; speedup vs baseline: 1.0754x; 1.0410x over previous
//
#include <hip/hip_runtime.h>
#include <cstdint>

typedef __attribute__((ext_vector_type(8))) short bf16x8;
typedef __attribute__((ext_vector_type(4))) float f32x4;
typedef unsigned short u16;
typedef uint32_t u32;

#define HW56 56
#define HWSQ 3136       // 56*56
#define MTOT 200704     // 64*3136
#define CCH 128
#define BM 128
#define NSTEP 18        // 9 taps * 2 K-halves (BK=64)
#define NBLK (MTOT / BM)        // 1568 = 8 * 196
#define NB_PER_XCD (NBLK / 8)   // 196

__device__ __forceinline__ u16 f2bf(float f) {
  u32 u = __builtin_bit_cast(u32, f);
  u = (u + 0x7fffu + ((u >> 16) & 1u)) >> 16;   // RNE
  return (u16)u;
}
__device__ __forceinline__ float bf2f(u16 h) {
  return __builtin_bit_cast(float, (u32)h << 16);
}
__device__ __forceinline__ void gload16(const void* g, void* l) {
  __builtin_amdgcn_global_load_lds((const __attribute__((address_space(1))) void*)g,
                                   (__attribute__((address_space(3))) void*)l, 16, 0, 0);
}

// ---------- pack x: NCHW f32 -> NHWC bf16, LDS-transposed so BOTH sides coalesce ----
__global__ __launch_bounds__(256) void pack_x_kernel(const float* __restrict__ x,
                                                     u16* __restrict__ xb) {
  __shared__ u16 t[128 * 65];                 // [c][pos], stride 65 (bank-friendly)
  const int tid = threadIdx.x;
  const int lane = tid & 63, wv = tid >> 6;
  const int p0 = blockIdx.x * 64;             // 64 pos, one image (3136 % 64 == 0)
  const int n = p0 / HWSQ, hw0 = p0 % HWSQ;
  const float* src = x + (size_t)(n * CCH) * HWSQ + hw0;
#pragma unroll
  for (int k = 0; k < 32; ++k) {              // coalesced 256B reads per instr
    const int c = wv * 32 + k;
    t[c * 65 + lane] = f2bf(src[(size_t)c * HWSQ + lane]);
  }
  __syncthreads();
  u16* dst = xb + (size_t)p0 * CCH;
#pragma unroll
  for (int it = 0; it < 4; ++it) {            // coalesced 1KB writes per wave-instr
    const int u = it * 256 + tid;
    const int pos = u >> 4, ch0 = (u & 15) * 8;
    u32 vv[4];
#pragma unroll
    for (int q = 0; q < 4; ++q) {
      const u16 a = t[(ch0 + 2 * q) * 65 + pos];
      const u16 b = t[(ch0 + 2 * q + 1) * 65 + pos];
      vv[q] = (u32)a | ((u32)b << 16);
    }
    uint4 v; v.x = vv[0]; v.y = vv[1]; v.z = vv[2]; v.w = vv[3];
    *(uint4*)(dst + (size_t)pos * CCH + ch0) = v;
  }
}

// ---------- pack weights: fold BN scale, [O][I][3][3] f32 -> [tap][oc][ic] bf16 ----------
__global__ __launch_bounds__(256) void pack_w_kernel(
    const float* __restrict__ w1, const float* __restrict__ w2,
    const float* __restrict__ g1, const float* __restrict__ be1,
    const float* __restrict__ mu1, const float* __restrict__ va1,
    const float* __restrict__ g2, const float* __restrict__ be2,
    const float* __restrict__ mu2, const float* __restrict__ va2,
    u16* __restrict__ w1p, u16* __restrict__ w2p,
    float* __restrict__ b1, float* __restrict__ b2, float* __restrict__ zp) {
  const int idx = blockIdx.x * 256 + threadIdx.x;   // grid = 294912/256
  if (idx < 2 * 147456) {
    const int which = idx >= 147456;
    const int j = which ? idx - 147456 : idx;
    const int t = j >> 14;            // tap 0..8
    const int oc = (j >> 7) & 127;
    const int ic = j & 127;
    const float* w = which ? w2 : w1;
    const float* gg = which ? g2 : g1;
    const float* va = which ? va2 : va1;
    const float s = gg[oc] * rsqrtf(va[oc] + 1e-5f);
    const float val = w[(size_t)(oc * 128 + ic) * 9 + t] * s;
    (which ? w2p : w1p)[j] = f2bf(val);
  }
  if (blockIdx.x == 0) {
    const int t = threadIdx.x;
    if (t < 128) {
      const float s1 = g1[t] * rsqrtf(va1[t] + 1e-5f);
      b1[t] = be1[t] - mu1[t] * s1;
      const float s2 = g2[t] * rsqrtf(va2[t] + 1e-5f);
      b2[t] = be2[t] - mu2[t] * s2;
    }
    if (t < 64) zp[t] = 0.f;          // 256B zero page (ws is re-poisoned each launch)
  }
}

// ---------- implicit-GEMM conv 3x3 (pad=1) with fused BN(+ReLU)(+residual) ----------
// src: NHWC bf16 activations; wp: [tap][oc][ic] bf16 (BN scale folded)
// PASS 1: out = relu(acc + b) -> bf16 NHWC (outb)
// PASS 2: out = relu(acc + b + residual) -> f32 NCHW (outf), via LDS transpose
// Sync structure: T4 counted-vmcnt depth-2 pipeline (raw s_barrier, vmcnt(8) not 0)
template <int PASS>
__global__ __launch_bounds__(256, 2) void conv_mfma(
    const u16* __restrict__ src, const u16* __restrict__ wp,
    const float* __restrict__ bias, const u16* __restrict__ resid,
    u16* __restrict__ outb, float* __restrict__ outf,
    const char* __restrict__ zp) {
  // LDS: A0 | A1 | B0 | B1 (16KB each). Rows of 128B (64 ic bf16), XOR-swizzled
  // content: slot s of row r holds source 16B-group s^(r&7).
  __shared__ __align__(1024) char lds[65536];
  const int tid = threadIdx.x;
  const int wave = tid >> 6, lane = tid & 63;
  // T1: XCD-chunked bijective swizzle (1568 % 8 == 0) — neighbor tiles share
  // 3x3 halos + weights -> keep them on one XCD's L2.
  const int bid = blockIdx.x;
  const int swz = (bid & 7) * NB_PER_XCD + (bid >> 3);
  const int m0 = swz * BM;
  const int wm = wave >> 1, wn = wave & 1;    // 2x2 wave grid, 64x64 tile each

  // Per-thread staging state: 4 rows (8-row groups), one 16B group each.
  const int g = lane & 7;
  int ah[4], aw[4];
  long long aoff[4], boff[4];
#pragma unroll
  for (int i = 0; i < 4; ++i) {
    const int r = wave * 32 + i * 8 + (lane >> 3);  // row 0..127
    const int pos = m0 + r;
    const int hw = pos % HWSQ;
    ah[i] = hw / HW56;
    aw[i] = hw % HW56;
    const int gsw = g ^ (r & 7);                    // pre-swizzled source group
    aoff[i] = (long long)pos * 256 + gsw * 16;      // NHWC row = 256B
    boff[i] = (long long)r * 256 + gsw * 16;        // w row (oc) = 256B
  }
  const char* srcb = (const char*)src;
  const char* wpb = (const char*)wp;

  auto stage = [&](int buf, int s) {                // 8 gload16 per thread
    const int t = s >> 1, kh = s & 1;
    const int dyo = t / 3 - 1, dxo = t % 3 - 1;
    const long long adelta = (long long)(dyo * HW56 + dxo) * 256 + kh * 128;
    const long long bdelta = (long long)t * 32768 + kh * 128;
    char* ldsA = lds + buf * 16384;
    char* ldsB = lds + 32768 + buf * 16384;
#pragma unroll
    for (int i = 0; i < 4; ++i) {
      const int hh = ah[i] + dyo, ww = aw[i] + dxo;
      const bool valid = ((unsigned)hh < 56u) & ((unsigned)ww < 56u);
      const char* ap = valid ? (srcb + aoff[i] + adelta) : zp;  // zero-pad via zero page
      gload16(ap, ldsA + (wave * 32 + i * 8) * 128);            // LDS dest wave-uniform
      gload16(wpb + boff[i] + bdelta, ldsB + (wave * 32 + i * 8) * 128);
    }
  };

  f32x4 acc[4][4];
#pragma unroll
  for (int m = 0; m < 4; ++m)
#pragma unroll
    for (int n = 0; n < 4; ++n) {
      f32x4 z = {0.f, 0.f, 0.f, 0.f};
      acc[m][n] = z;
    }

  auto compute = [&](int buf) {
    const char* ldsA = lds + buf * 16384;
    const char* ldsB = lds + 32768 + buf * 16384;
    bf16x8 a[4][2], b[4][2];
#pragma unroll
    for (int m = 0; m < 4; ++m) {
      const int row = wm * 64 + m * 16 + (lane & 15);
      const char* rp = ldsA + row * 128;
      const int sw = row & 7;
#pragma unroll
      for (int ks = 0; ks < 2; ++ks) {
        const int gg = ks * 4 + (lane >> 4);                  // k-group: ks*32 + (lane>>4)*8
        a[m][ks] = *(const bf16x8*)(rp + ((gg ^ sw) << 4));   // swizzled ds_read_b128
      }
    }
#pragma unroll
    for (int n = 0; n < 4; ++n) {
      const int row = wn * 64 + n * 16 + (lane & 15);
      const char* rp = ldsB + row * 128;
      const int sw = row & 7;
#pragma unroll
      for (int ks = 0; ks < 2; ++ks) {
        const int gg = ks * 4 + (lane >> 4);
        b[n][ks] = *(const bf16x8*)(rp + ((gg ^ sw) << 4));
      }
    }
    __builtin_amdgcn_s_setprio(1);                 // T5: favor MFMA cluster
#pragma unroll
    for (int ks = 0; ks < 2; ++ks)
#pragma unroll
      for (int m = 0; m < 4; ++m)
#pragma unroll
        for (int n = 0; n < 4; ++n)
          acc[m][n] = __builtin_amdgcn_mfma_f32_16x16x32_bf16(a[m][ks], b[n][ks],
                                                              acc[m][n], 0, 0, 0);
    __builtin_amdgcn_s_setprio(0);
  };

  stage(0, 0);                                     // 8 loads in flight
#pragma unroll
  for (int s = 0; s < NSTEP; ++s) {
    const int cur = s & 1;
    if (s + 1 < NSTEP) {
      stage(cur ^ 1, s + 1);                       // +8 loads (16 in flight)
      asm volatile("s_waitcnt vmcnt(8)" ::: "memory");   // stage(s) done; s+1 stays in flight
    } else {
      asm volatile("s_waitcnt vmcnt(0)" ::: "memory");   // tail: drain last stage
    }
    __builtin_amdgcn_s_barrier();                  // all waves' stage(s) landed
    __builtin_amdgcn_sched_barrier(0);             // pin ds_reads below barrier (rule #18)
    compute(cur);
    __builtin_amdgcn_sched_barrier(0);             // pin ds_reads/MFMA above barrier
    __builtin_amdgcn_s_barrier();                  // buf s free for overwrite at s+2
  }
  __syncthreads();                                 // full drain before epilogue LDS reuse

  if (PASS == 1) {
#pragma unroll
    for (int nf = 0; nf < 4; ++nf) {
      const int oc = wn * 64 + nf * 16 + (lane & 15);
      const float bb = bias[oc];
#pragma unroll
      for (int m = 0; m < 4; ++m) {
        const int pbase = m0 + wm * 64 + m * 16 + (lane >> 4) * 4;
#pragma unroll
        for (int r = 0; r < 4; ++r) {
          float v = acc[m][nf][r] + bb;
          v = fmaxf(v, 0.f);
          outb[(size_t)(pbase + r) * CCH + oc] = f2bf(v);
        }
      }
    }
  } else {
    // epilogue: bias + residual + relu, then per-wave LDS transpose -> coalesced NCHW f32
    float* tl = (float*)(lds + wave * 4352);     // [64][17] f32, wave-private
    const int posr = m0 + wm * 64 + lane;
    const int nimg = posr / HWSQ, hwr = posr % HWSQ;
#pragma unroll
    for (int nf = 0; nf < 4; ++nf) {
      const int oc = wn * 64 + nf * 16 + (lane & 15);
      const float bb = bias[oc];
#pragma unroll
      for (int m = 0; m < 4; ++m) {
#pragma unroll
        for (int r = 0; r < 4; ++r) {
          const int row = m * 16 + (lane >> 4) * 4 + r;
          const int pos = m0 + wm * 64 + row;
          const float rv = bf2f(resid[(size_t)pos * CCH + oc]);
          float v = acc[m][nf][r] + bb + rv;
          tl[row * 17 + (lane & 15)] = fmaxf(v, 0.f);
        }
      }
      // compiler inserts lgkmcnt waits for the within-wave LDS RAW/WAR here
#pragma unroll
      for (int oci = 0; oci < 16; ++oci) {
        const float v = tl[lane * 17 + oci];
        const int oc2 = wn * 64 + nf * 16 + oci;
        outf[(size_t)(nimg * CCH + oc2) * HWSQ + hwr] = v;   // 64 consecutive hw per store
      }
    }
  }
}

extern "C" void kernel_launch(void* const* d_in, const int* in_sizes, int n_in,
                              void* d_out, int out_size, void* d_ws, size_t ws_size,
                              hipStream_t stream) {
  const float* x = (const float*)d_in[0];
  const float* w1 = (const float*)d_in[1];
  const float* w2 = (const float*)d_in[2];
  const float* g1 = (const float*)d_in[3];
  const float* be1 = (const float*)d_in[4];
  const float* mu1 = (const float*)d_in[5];
  const float* va1 = (const float*)d_in[6];
  const float* g2 = (const float*)d_in[7];
  const float* be2 = (const float*)d_in[8];
  const float* mu2 = (const float*)d_in[9];
  const float* va2 = (const float*)d_in[10];

  char* ws = (char*)d_ws;
  u16* xb  = (u16*)(ws + 0);                    // 200704*128*2 = 51,380,224 B
  u16* o1b = (u16*)(ws + 51380224);             // 51,380,224 B
  u16* w1p = (u16*)(ws + 102760448);            // 294,912 B
  u16* w2p = (u16*)(ws + 103055360);            // 294,912 B
  float* b1 = (float*)(ws + 103350272);         // 512 B
  float* b2 = (float*)(ws + 103350784);         // 512 B
  float* zp = (float*)(ws + 103351296);         // 256 B zero page

  pack_x_kernel<<<MTOT / 64, 256, 0, stream>>>(x, xb);
  pack_w_kernel<<<1152, 256, 0, stream>>>(w1, w2, g1, be1, mu1, va1,
                                          g2, be2, mu2, va2, w1p, w2p, b1, b2, zp);
  conv_mfma<1><<<NBLK, 256, 0, stream>>>(xb, w1p, b1, nullptr, o1b, nullptr,
                                         (const char*)zp);
  conv_mfma<2><<<NBLK, 256, 0, stream>>>(o1b, w2p, b2, xb, nullptr, (float*)d_out,
                                         (const char*)zp);
}